// Round 5
// baseline (340.759 us; speedup 1.0000x reference)
//
#include <hip/hip_runtime.h>
#include <math.h>

#define B_   256
#define S_   4
#define W1_  64
#define W2_  128
#define D_   300
#define HID_ 4

typedef float          fx4   __attribute__((ext_vector_type(4)));
typedef short          s16x8 __attribute__((ext_vector_type(8)));
typedef unsigned int   ux4   __attribute__((ext_vector_type(4)));

__device__ __forceinline__ unsigned bf16_rne(float x) {
    unsigned u = __float_as_uint(x);
    return (u + 0x7FFFu + ((u >> 16) & 1u)) >> 16;   // bf16 in low 16 bits
}

// Split 8 consecutive-k f32 (two fx4) into hi/lo bf16x8 MFMA fragments.
// x ~= hi + lo with ~2^-17 relative residual (round-4 verified absmax 0).
__device__ __forceinline__ void cvt8(const fx4 x0, const fx4 x1, s16x8& hi, s16x8& lo) {
    ux4 hu, lu;
#pragma unroll
    for (int p = 0; p < 4; ++p) {
        float a = (p < 2) ? x0[2 * p]     : x1[2 * p - 4];
        float b = (p < 2) ? x0[2 * p + 1] : x1[2 * p - 3];
        unsigned ha = bf16_rne(a), hb = bf16_rne(b);
        float haf = __uint_as_float(ha << 16);
        float hbf = __uint_as_float(hb << 16);
        unsigned la = bf16_rne(a - haf), lb = bf16_rne(b - hbf);
        hu[p] = ha | (hb << 16);
        lu[p] = la | (lb << 16);
    }
    hi = __builtin_bit_cast(s16x8, hu);
    lo = __builtin_bit_cast(s16x8, lu);
}

// Barrier-free MFMA similarity-count. Block = one (b,s) slot = 4 independent
// waves; wave (rowHalf=w>>1, colHalf=w&1) owns a 32x64 output tile.
// MFMA fragments (8 contiguous k per lane, row/col = l&15 — verified round 4)
// are loaded DIRECTLY from global: no LDS, no __syncthreads. Register
// ping-pong software pipeline keeps 12 KB/wave of loads in flight.
__global__ __launch_bounds__(256, 2) void sim_count_mfma(
    const float* __restrict__ t1, const float* __restrict__ t2,
    const int* __restrict__ m1, const int* __restrict__ m2,
    const float* __restrict__ thr_p, int* __restrict__ cnt)
{
    const int slot = blockIdx.x;
    const int tid  = threadIdx.x;
    const int l    = tid & 63;
    const int w    = tid >> 6;
    const int rowHalf = w >> 1, colHalf = w & 1;
    const int lr   = l & 15;
    const int lg8  = (l >> 4) * 8;          // frag k-offset within 32-step
    const float thr = *thr_p;

    const float* aP[2];
    const float* bP[4];
#pragma unroll
    for (int rt = 0; rt < 2; ++rt)
        aP[rt] = t1 + (size_t)slot * W1_ * D_ + (size_t)(rowHalf * 32 + rt * 16 + lr) * D_ + lg8;
#pragma unroll
    for (int ct = 0; ct < 4; ++ct)
        bP[ct] = t2 + (size_t)slot * W2_ * D_ + (size_t)(colHalf * 64 + ct * 16 + lr) * D_ + lg8;

    fx4 acc[2][4];
#pragma unroll
    for (int rt = 0; rt < 2; ++rt)
#pragma unroll
        for (int ct = 0; ct < 4; ++ct) {
            fx4 z; z[0] = 0.f; z[1] = 0.f; z[2] = 0.f; z[3] = 0.f;
            acc[rt][ct] = z;
        }

    // K-step t covers k = 32t .. 32t+31 (t=0..9; t=9 partially valid, k<300).
    auto issue_full = [&](fx4 (&SA)[2][2], fx4 (&SB)[4][2], int t) {
#pragma unroll
        for (int rt = 0; rt < 2; ++rt) {
            const float* p = aP[rt] + t * 32;
            SA[rt][0] = *(const fx4*)p;
            SA[rt][1] = *(const fx4*)(p + 4);
        }
#pragma unroll
        for (int ct = 0; ct < 4; ++ct) {
            const float* p = bP[ct] + t * 32;
            SB[ct][0] = *(const fx4*)p;
            SB[ct][1] = *(const fx4*)(p + 4);
        }
    };
    // Tail t=9: valid lanes: lg8=0 -> k 288..295 (full), lg8=8 -> 296..299
    // (first fx4 only), lg8>=16 -> nothing (zeros).
    auto issue_tail = [&](fx4 (&SA)[2][2], fx4 (&SB)[4][2]) {
        fx4 z; z[0] = 0.f; z[1] = 0.f; z[2] = 0.f; z[3] = 0.f;
#pragma unroll
        for (int rt = 0; rt < 2; ++rt) {
            const float* p = aP[rt] + 288;
            SA[rt][0] = z; SA[rt][1] = z;
            if (lg8 < 16) SA[rt][0] = *(const fx4*)p;
            if (lg8 == 0) SA[rt][1] = *(const fx4*)(p + 4);
        }
#pragma unroll
        for (int ct = 0; ct < 4; ++ct) {
            const float* p = bP[ct] + 288;
            SB[ct][0] = z; SB[ct][1] = z;
            if (lg8 < 16) SB[ct][0] = *(const fx4*)p;
            if (lg8 == 0) SB[ct][1] = *(const fx4*)(p + 4);
        }
    };
    auto compute = [&](fx4 (&SA)[2][2], fx4 (&SB)[4][2]) {
        s16x8 ah[2], al[2];
#pragma unroll
        for (int rt = 0; rt < 2; ++rt) cvt8(SA[rt][0], SA[rt][1], ah[rt], al[rt]);
#pragma unroll
        for (int ct = 0; ct < 4; ++ct) {
            s16x8 bh, bl;
            cvt8(SB[ct][0], SB[ct][1], bh, bl);
#pragma unroll
            for (int rt = 0; rt < 2; ++rt) {
                acc[rt][ct] = __builtin_amdgcn_mfma_f32_16x16x32_bf16(ah[rt], bh, acc[rt][ct], 0, 0, 0);
                acc[rt][ct] = __builtin_amdgcn_mfma_f32_16x16x32_bf16(ah[rt], bl, acc[rt][ct], 0, 0, 0);
                acc[rt][ct] = __builtin_amdgcn_mfma_f32_16x16x32_bf16(al[rt], bh, acc[rt][ct], 0, 0, 0);
            }
        }
    };

    // Software pipeline: named ping-pong buffers, all indices compile-time.
    fx4 s0A[2][2], s0B[4][2], s1A[2][2], s1B[4][2];
    issue_full(s0A, s0B, 0);
#pragma unroll
    for (int tt = 0; tt < 4; ++tt) {
        issue_full(s1A, s1B, 2 * tt + 1);
        compute(s0A, s0B);
        issue_full(s0A, s0B, 2 * tt + 2);   // t = 2,4,6,8
        compute(s1A, s1B);
    }
    issue_tail(s1A, s1B);                   // t = 9
    compute(s0A, s0B);                      // t = 8
    compute(s1A, s1B);                      // t = 9

    // --- masked threshold count. C/D: col = ct*16 + (l&15), row = rt*16 + (l>>4)*4 + r ---
    int am[2][4];
#pragma unroll
    for (int rt = 0; rt < 2; ++rt)
#pragma unroll
        for (int r = 0; r < 4; ++r)
            am[rt][r] = m1[slot * W1_ + rowHalf * 32 + rt * 16 + (l >> 4) * 4 + r];
    int bm[4];
#pragma unroll
    for (int ct = 0; ct < 4; ++ct)
        bm[ct] = m2[slot * W2_ + colHalf * 64 + ct * 16 + lr];

    int lc = 0;
#pragma unroll
    for (int rt = 0; rt < 2; ++rt)
#pragma unroll
        for (int ct = 0; ct < 4; ++ct)
#pragma unroll
            for (int r = 0; r < 4; ++r)
                lc += ((acc[rt][ct][r] >= thr) & (am[rt][r] != 0) & (bm[ct] != 0)) ? 1 : 0;
#pragma unroll
    for (int o = 32; o > 0; o >>= 1) lc += __shfl_down(lc, o);
    if (l == 0) atomicAdd(&cnt[slot], lc);   // device-scope, cross-XCD safe
}

// Finalize: norm = cnt / nA (nA recomputed from m1), then MLP head.
__global__ __launch_bounds__(256) void finalize_head(
    const int* __restrict__ cnt, const int* __restrict__ m1,
    const float* __restrict__ Wh,   // (S, HID) row-major
    const float* __restrict__ Ws,   // (HID, 1)
    float* __restrict__ out)
{
    int b = blockIdx.x * blockDim.x + threadIdx.x;
    if (b >= B_) return;
    float n[4];
#pragma unroll
    for (int s = 0; s < 4; ++s) {
        const int slot = b * 4 + s;
        int nA = 0;
        const int4* mp = (const int4*)(m1 + slot * W1_);
#pragma unroll
        for (int g = 0; g < 16; ++g) {
            int4 v = mp[g];
            nA += (v.x != 0) + (v.y != 0) + (v.z != 0) + (v.w != 0);
        }
        const float divisor = (nA == 0) ? 1e-7f : (float)nA;
        n[s] = (float)cnt[slot] / divisor;
    }
    float score = 0.f;
#pragma unroll
    for (int j = 0; j < HID_; ++j) {
        float h = n[0] * Wh[0 * HID_ + j] + n[1] * Wh[1 * HID_ + j]
                + n[2] * Wh[2 * HID_ + j] + n[3] * Wh[3 * HID_ + j];
        h = tanhf(h);
        score += h * Ws[j];
    }
    out[b] = 1.f / (1.f + expf(-score));
}

extern "C" void kernel_launch(void* const* d_in, const int* in_sizes, int n_in,
                              void* d_out, int out_size, void* d_ws, size_t ws_size,
                              hipStream_t stream)
{
    const float* t1  = (const float*)d_in[0];
    const float* t2  = (const float*)d_in[1];
    const int*   m1  = (const int*)d_in[2];
    const int*   m2  = (const int*)d_in[3];
    const float* thr = (const float*)d_in[4];
    const float* Wh  = (const float*)d_in[5];
    const float* Ws  = (const float*)d_in[6];
    float* out = (float*)d_out;
    int*   cnt = (int*)d_ws;   // 1024 ints

    hipMemsetAsync(cnt, 0, B_ * S_ * sizeof(int), stream);
    sim_count_mfma<<<B_ * S_, 256, 0, stream>>>(t1, t2, m1, m2, thr, cnt);
    finalize_head<<<1, 256, 0, stream>>>(cnt, m1, Wh, Ws, out);
}

// Round 8
// 308.396 us; speedup vs baseline: 1.1049x; 1.1049x over previous
//
#include <hip/hip_runtime.h>
#include <math.h>

#define B_   256
#define S_   4
#define W1_  64
#define W2_  128
#define D_   300
#define HID_ 4

typedef float          fx4   __attribute__((ext_vector_type(4)));
typedef short          s16x8 __attribute__((ext_vector_type(8)));
typedef unsigned int   ux4   __attribute__((ext_vector_type(4)));

__device__ __forceinline__ unsigned bf16_rne(float x) {
    unsigned u = __float_as_uint(x);
    return (u + 0x7FFFu + ((u >> 16) & 1u)) >> 16;   // bf16 in low 16 bits
}

// Split 8 consecutive-k f32 (two fx4) into hi/lo bf16x8 MFMA fragments.
// x ~= hi + lo with ~2^-17 relative residual (round-4/5 verified absmax 0).
__device__ __forceinline__ void cvt8(const fx4 x0, const fx4 x1, s16x8& hi, s16x8& lo) {
    ux4 hu, lu;
#pragma unroll
    for (int p = 0; p < 4; ++p) {
        float a = (p < 2) ? x0[2 * p]     : x1[2 * p - 4];
        float b = (p < 2) ? x0[2 * p + 1] : x1[2 * p - 3];
        unsigned ha = bf16_rne(a), hb = bf16_rne(b);
        float haf = __uint_as_float(ha << 16);
        float hbf = __uint_as_float(hb << 16);
        unsigned la = bf16_rne(a - haf), lb = bf16_rne(b - hbf);
        hu[p] = ha | (hb << 16);
        lu[p] = la | (lb << 16);
    }
    hi = __builtin_bit_cast(s16x8, hu);
    lo = __builtin_bit_cast(s16x8, lu);
}

// Barrier-free MFMA similarity-count. Block = one (b,s) slot = 4 independent
// waves; wave (rowHalf=w>>1, colHalf=w&1) owns a 32x64 output tile.
// MFMA fragments (8 contiguous k per lane) loaded DIRECTLY from global.
// Round-5 lesson: without a scheduling fence the compiler deallocates the
// ping-pong (VGPR=80) and serializes loads (~1.9 KB/CU in flight). The
// sched_barrier(0) after each issue phase pins {12 loads} BEFORE the previous
// tile's compute in the emitted ISA, keeping 12 KB/wave outstanding.
__global__ __launch_bounds__(256, 2) void sim_count_mfma(
    const float* __restrict__ t1, const float* __restrict__ t2,
    const int* __restrict__ m1, const int* __restrict__ m2,
    const float* __restrict__ thr_p, int* __restrict__ cnt)
{
    const int slot = blockIdx.x;
    const int tid  = threadIdx.x;
    const int l    = tid & 63;
    const int w    = tid >> 6;
    const int rowHalf = w >> 1, colHalf = w & 1;
    const int lr   = l & 15;
    const int lg8  = (l >> 4) * 8;          // frag k-offset within 32-step
    const float thr = *thr_p;

    const float* aP[2];
    const float* bP[4];
#pragma unroll
    for (int rt = 0; rt < 2; ++rt)
        aP[rt] = t1 + (size_t)slot * W1_ * D_ + (size_t)(rowHalf * 32 + rt * 16 + lr) * D_ + lg8;
#pragma unroll
    for (int ct = 0; ct < 4; ++ct)
        bP[ct] = t2 + (size_t)slot * W2_ * D_ + (size_t)(colHalf * 64 + ct * 16 + lr) * D_ + lg8;

    fx4 acc[2][4];
#pragma unroll
    for (int rt = 0; rt < 2; ++rt)
#pragma unroll
        for (int ct = 0; ct < 4; ++ct) {
            fx4 z; z[0] = 0.f; z[1] = 0.f; z[2] = 0.f; z[3] = 0.f;
            acc[rt][ct] = z;
        }

    // K-step t covers k = 32t .. 32t+31 (t=0..9; t=9 partially valid, k<300).
    auto issue_full = [&](fx4 (&SA)[2][2], fx4 (&SB)[4][2], int t) {
#pragma unroll
        for (int rt = 0; rt < 2; ++rt) {
            const float* p = aP[rt] + t * 32;
            SA[rt][0] = *(const fx4*)p;
            SA[rt][1] = *(const fx4*)(p + 4);
        }
#pragma unroll
        for (int ct = 0; ct < 4; ++ct) {
            const float* p = bP[ct] + t * 32;
            SB[ct][0] = *(const fx4*)p;
            SB[ct][1] = *(const fx4*)(p + 4);
        }
    };
    // Tail t=9: lg8=0 -> k 288..295 (full), lg8=8 -> 296..299 (first fx4),
    // lg8>=16 -> zeros.
    auto issue_tail = [&](fx4 (&SA)[2][2], fx4 (&SB)[4][2]) {
        fx4 z; z[0] = 0.f; z[1] = 0.f; z[2] = 0.f; z[3] = 0.f;
#pragma unroll
        for (int rt = 0; rt < 2; ++rt) {
            const float* p = aP[rt] + 288;
            SA[rt][0] = z; SA[rt][1] = z;
            if (lg8 < 16) SA[rt][0] = *(const fx4*)p;
            if (lg8 == 0) SA[rt][1] = *(const fx4*)(p + 4);
        }
#pragma unroll
        for (int ct = 0; ct < 4; ++ct) {
            const float* p = bP[ct] + 288;
            SB[ct][0] = z; SB[ct][1] = z;
            if (lg8 < 16) SB[ct][0] = *(const fx4*)p;
            if (lg8 == 0) SB[ct][1] = *(const fx4*)(p + 4);
        }
    };
    auto compute = [&](fx4 (&SA)[2][2], fx4 (&SB)[4][2]) {
        s16x8 ah[2], al[2];
#pragma unroll
        for (int rt = 0; rt < 2; ++rt) cvt8(SA[rt][0], SA[rt][1], ah[rt], al[rt]);
#pragma unroll
        for (int ct = 0; ct < 4; ++ct) {
            s16x8 bh, bl;
            cvt8(SB[ct][0], SB[ct][1], bh, bl);
#pragma unroll
            for (int rt = 0; rt < 2; ++rt) {
                acc[rt][ct] = __builtin_amdgcn_mfma_f32_16x16x32_bf16(ah[rt], bh, acc[rt][ct], 0, 0, 0);
                acc[rt][ct] = __builtin_amdgcn_mfma_f32_16x16x32_bf16(ah[rt], bl, acc[rt][ct], 0, 0, 0);
                acc[rt][ct] = __builtin_amdgcn_mfma_f32_16x16x32_bf16(al[rt], bh, acc[rt][ct], 0, 0, 0);
            }
        }
    };

    // Software pipeline, order pinned by sched_barrier(0) at each boundary:
    //   [issue tile t+1] <fence> [compute tile t] ...
    fx4 s0A[2][2], s0B[4][2], s1A[2][2], s1B[4][2];
    issue_full(s0A, s0B, 0);
    __builtin_amdgcn_sched_barrier(0);
#pragma unroll
    for (int tt = 0; tt < 4; ++tt) {
        issue_full(s1A, s1B, 2 * tt + 1);
        __builtin_amdgcn_sched_barrier(0);
        compute(s0A, s0B);
        __builtin_amdgcn_sched_barrier(0);
        issue_full(s0A, s0B, 2 * tt + 2);   // t = 2,4,6,8
        __builtin_amdgcn_sched_barrier(0);
        compute(s1A, s1B);
        __builtin_amdgcn_sched_barrier(0);
    }
    issue_tail(s1A, s1B);                   // t = 9
    __builtin_amdgcn_sched_barrier(0);
    compute(s0A, s0B);                      // t = 8
    compute(s1A, s1B);                      // t = 9

    // --- masked threshold count. C/D: col = ct*16 + (l&15), row = rt*16 + (l>>4)*4 + r ---
    int am[2][4];
#pragma unroll
    for (int rt = 0; rt < 2; ++rt)
#pragma unroll
        for (int r = 0; r < 4; ++r)
            am[rt][r] = m1[slot * W1_ + rowHalf * 32 + rt * 16 + (l >> 4) * 4 + r];
    int bm[4];
#pragma unroll
    for (int ct = 0; ct < 4; ++ct)
        bm[ct] = m2[slot * W2_ + colHalf * 64 + ct * 16 + lr];

    int lc = 0;
#pragma unroll
    for (int rt = 0; rt < 2; ++rt)
#pragma unroll
        for (int ct = 0; ct < 4; ++ct)
#pragma unroll
            for (int r = 0; r < 4; ++r)
                lc += ((acc[rt][ct][r] >= thr) & (am[rt][r] != 0) & (bm[ct] != 0)) ? 1 : 0;
#pragma unroll
    for (int o = 32; o > 0; o >>= 1) lc += __shfl_down(lc, o);
    if (l == 0) atomicAdd(&cnt[slot], lc);   // device-scope, cross-XCD safe
}

// Finalize: norm = cnt / nA (nA recomputed from m1), then MLP head.
__global__ __launch_bounds__(256) void finalize_head(
    const int* __restrict__ cnt, const int* __restrict__ m1,
    const float* __restrict__ Wh,   // (S, HID) row-major
    const float* __restrict__ Ws,   // (HID, 1)
    float* __restrict__ out)
{
    int b = blockIdx.x * blockDim.x + threadIdx.x;
    if (b >= B_) return;
    float n[4];
#pragma unroll
    for (int s = 0; s < 4; ++s) {
        const int slot = b * 4 + s;
        int nA = 0;
        const int4* mp = (const int4*)(m1 + slot * W1_);
#pragma unroll
        for (int g = 0; g < 16; ++g) {
            int4 v = mp[g];
            nA += (v.x != 0) + (v.y != 0) + (v.z != 0) + (v.w != 0);
        }
        const float divisor = (nA == 0) ? 1e-7f : (float)nA;
        n[s] = (float)cnt[slot] / divisor;
    }
    float score = 0.f;
#pragma unroll
    for (int j = 0; j < HID_; ++j) {
        float h = n[0] * Wh[0 * HID_ + j] + n[1] * Wh[1 * HID_ + j]
                + n[2] * Wh[2 * HID_ + j] + n[3] * Wh[3 * HID_ + j];
        h = tanhf(h);
        score += h * Ws[j];
    }
    out[b] = 1.f / (1.f + expf(-score));
}

extern "C" void kernel_launch(void* const* d_in, const int* in_sizes, int n_in,
                              void* d_out, int out_size, void* d_ws, size_t ws_size,
                              hipStream_t stream)
{
    const float* t1  = (const float*)d_in[0];
    const float* t2  = (const float*)d_in[1];
    const int*   m1  = (const int*)d_in[2];
    const int*   m2  = (const int*)d_in[3];
    const float* thr = (const float*)d_in[4];
    const float* Wh  = (const float*)d_in[5];
    const float* Ws  = (const float*)d_in[6];
    float* out = (float*)d_out;
    int*   cnt = (int*)d_ws;   // 1024 ints

    hipMemsetAsync(cnt, 0, B_ * S_ * sizeof(int), stream);
    sim_count_mfma<<<B_ * S_, 256, 0, stream>>>(t1, t2, m1, m2, thr, cnt);
    finalize_head<<<1, 256, 0, stream>>>(cnt, m1, Wh, Ws, out);
}

// Round 9
// 306.947 us; speedup vs baseline: 1.1102x; 1.0047x over previous
//
#include <hip/hip_runtime.h>
#include <math.h>

#define B_   256
#define S_   4
#define W1_  64
#define W2_  128
#define D_   300
#define HID_ 4

typedef float          fx4   __attribute__((ext_vector_type(4)));
typedef short          s16x8 __attribute__((ext_vector_type(8)));
typedef unsigned int   ux4   __attribute__((ext_vector_type(4)));

__device__ __forceinline__ unsigned bf16_rne(float x) {
    unsigned u = __float_as_uint(x);
    return (u + 0x7FFFu + ((u >> 16) & 1u)) >> 16;   // bf16 in low 16 bits
}

// Split 8 consecutive-k f32 (two fx4) into hi/lo bf16x8 MFMA fragments.
// x ~= hi + lo with ~2^-17 relative residual (rounds 4/5/8 verified absmax 0).
__device__ __forceinline__ void cvt8(const fx4 x0, const fx4 x1, s16x8& hi, s16x8& lo) {
    ux4 hu, lu;
#pragma unroll
    for (int p = 0; p < 4; ++p) {
        float a = (p < 2) ? x0[2 * p]     : x1[2 * p - 4];
        float b = (p < 2) ? x0[2 * p + 1] : x1[2 * p - 3];
        unsigned ha = bf16_rne(a), hb = bf16_rne(b);
        float haf = __uint_as_float(ha << 16);
        float hbf = __uint_as_float(hb << 16);
        unsigned la = bf16_rne(a - haf), lb = bf16_rne(b - hbf);
        hu[p] = ha | (hb << 16);
        lu[p] = la | (lb << 16);
    }
    hi = __builtin_bit_cast(s16x8, hu);
    lo = __builtin_bit_cast(s16x8, lu);
}

// Inline-asm 16B load with compile-time byte offset. The "=v" output forces
// the destination registers to be materialized and live until use — the
// compiler CANNOT sink this next to its consumer (rounds 5-8: every plain-load
// variant was dissolved by regalloc, VGPR=80-84, ~2 loads in flight).
template <int OFF>
__device__ __forceinline__ void gload(fx4& d, const float* p) {
    asm volatile("global_load_dwordx4 %0, %1, off offset:%c2"
                 : "=v"(d) : "v"(p), "i"(OFF));
}

#define FENCE  __builtin_amdgcn_sched_barrier(0)
#define WAIT24 do { asm volatile("s_waitcnt vmcnt(24)" ::: "memory"); FENCE; } while (0)
#define WAIT12 do { asm volatile("s_waitcnt vmcnt(12)" ::: "memory"); FENCE; } while (0)
#define WAIT0  do { asm volatile("s_waitcnt vmcnt(0)"  ::: "memory"); FENCE; } while (0)

// Issue all 12 loads of K-tile T (byte offset T*128, second half +16).
#define ISSUE(T, AA, BB) do { \
    gload<(T)*128>(AA[0][0], aP0); gload<(T)*128+16>(AA[0][1], aP0); \
    gload<(T)*128>(AA[1][0], aP1); gload<(T)*128+16>(AA[1][1], aP1); \
    gload<(T)*128>(BB[0][0], bP0); gload<(T)*128+16>(BB[0][1], bP0); \
    gload<(T)*128>(BB[1][0], bP1); gload<(T)*128+16>(BB[1][1], bP1); \
    gload<(T)*128>(BB[2][0], bP2); gload<(T)*128+16>(BB[2][1], bP2); \
    gload<(T)*128>(BB[3][0], bP3); gload<(T)*128+16>(BB[3][1], bP3); \
    FENCE; } while (0)

// Barrier-free MFMA similarity-count. Block = one (b,s) slot = 4 independent
// waves; wave (rowHalf, colHalf) owns a 32x64 output tile. Fragments loaded
// directly from global via asm, depth-3 pipeline, counted vmcnt (never
// drained to 0 in steady state — AITER pattern). No LDS, no __syncthreads.
// NOTE: no plain global loads may appear before/inside the pipeline (they
// would corrupt the vmcnt ledger) — thr/mask loads happen after WAIT0.
__global__ __launch_bounds__(256, 2) void sim_count_mfma(
    const float* __restrict__ t1, const float* __restrict__ t2,
    const int* __restrict__ m1, const int* __restrict__ m2,
    const float* __restrict__ thr_p, int* __restrict__ cnt)
{
    const int slot = blockIdx.x;
    const int tid  = threadIdx.x;
    const int l    = tid & 63;
    const int w    = tid >> 6;
    const int rowHalf = w >> 1, colHalf = w & 1;
    const int lr   = l & 15;
    const int lg8  = (l >> 4) * 8;          // frag k-offset within 32-step

    const float* t1b = t1 + (size_t)slot * W1_ * D_;
    const float* t2b = t2 + (size_t)slot * W2_ * D_;
    const float* aP0 = t1b + (size_t)(rowHalf * 32 +  0 + lr) * D_ + lg8;
    const float* aP1 = t1b + (size_t)(rowHalf * 32 + 16 + lr) * D_ + lg8;
    const float* bP0 = t2b + (size_t)(colHalf * 64 +  0 + lr) * D_ + lg8;
    const float* bP1 = t2b + (size_t)(colHalf * 64 + 16 + lr) * D_ + lg8;
    const float* bP2 = t2b + (size_t)(colHalf * 64 + 32 + lr) * D_ + lg8;
    const float* bP3 = t2b + (size_t)(colHalf * 64 + 48 + lr) * D_ + lg8;

    fx4 acc[2][4];
#pragma unroll
    for (int rt = 0; rt < 2; ++rt)
#pragma unroll
        for (int ct = 0; ct < 4; ++ct) {
            fx4 z; z[0] = 0.f; z[1] = 0.f; z[2] = 0.f; z[3] = 0.f;
            acc[rt][ct] = z;
        }

    auto compute = [&](fx4 (&SA)[2][2], fx4 (&SB)[4][2]) {
        s16x8 ah[2], al[2];
#pragma unroll
        for (int rt = 0; rt < 2; ++rt) cvt8(SA[rt][0], SA[rt][1], ah[rt], al[rt]);
#pragma unroll
        for (int ct = 0; ct < 4; ++ct) {
            s16x8 bh, bl;
            cvt8(SB[ct][0], SB[ct][1], bh, bl);
#pragma unroll
            for (int rt = 0; rt < 2; ++rt) {
                acc[rt][ct] = __builtin_amdgcn_mfma_f32_16x16x32_bf16(ah[rt], bh, acc[rt][ct], 0, 0, 0);
                acc[rt][ct] = __builtin_amdgcn_mfma_f32_16x16x32_bf16(ah[rt], bl, acc[rt][ct], 0, 0, 0);
                acc[rt][ct] = __builtin_amdgcn_mfma_f32_16x16x32_bf16(al[rt], bh, acc[rt][ct], 0, 0, 0);
            }
        }
    };

    // Depth-3 rotation over named buffers (no runtime buffer indexing).
    fx4 A0[2][2], B0[4][2], A1[2][2], B1[4][2], A2[2][2], B2[4][2];

    ISSUE(0, A0, B0);                       // 12 outstanding
    ISSUE(1, A1, B1);                       // 24
    ISSUE(2, A2, B2);                       // 36
    WAIT24; compute(A0, B0); FENCE; ISSUE(3, A0, B0);   // t=0; 36
    WAIT24; compute(A1, B1); FENCE; ISSUE(4, A1, B1);   // t=1
    WAIT24; compute(A2, B2); FENCE; ISSUE(5, A2, B2);   // t=2
    WAIT24; compute(A0, B0); FENCE; ISSUE(6, A0, B0);   // t=3
    WAIT24; compute(A1, B1); FENCE; ISSUE(7, A1, B1);   // t=4
    WAIT24; compute(A2, B2); FENCE; ISSUE(8, A2, B2);   // t=5
    WAIT24; compute(A0, B0); FENCE;                     // t=6; 24 left
    WAIT12; compute(A1, B1); FENCE;                     // t=7; 12 left
    WAIT0;  compute(A2, B2); FENCE;                     // t=8; 0 left

    // Tail t=9 (k=288..299, zero-padded): plain predicated loads are safe now
    // (vmcnt is 0; compiler tracks these normally).
    {
        fx4 z; z[0] = 0.f; z[1] = 0.f; z[2] = 0.f; z[3] = 0.f;
        A0[0][0] = z; A0[0][1] = z; A0[1][0] = z; A0[1][1] = z;
        B0[0][0] = z; B0[0][1] = z; B0[1][0] = z; B0[1][1] = z;
        B0[2][0] = z; B0[2][1] = z; B0[3][0] = z; B0[3][1] = z;
        if (lg8 < 16) {
            A0[0][0] = *(const fx4*)(aP0 + 288);
            A0[1][0] = *(const fx4*)(aP1 + 288);
            B0[0][0] = *(const fx4*)(bP0 + 288);
            B0[1][0] = *(const fx4*)(bP1 + 288);
            B0[2][0] = *(const fx4*)(bP2 + 288);
            B0[3][0] = *(const fx4*)(bP3 + 288);
        }
        if (lg8 == 0) {
            A0[0][1] = *(const fx4*)(aP0 + 292);
            A0[1][1] = *(const fx4*)(aP1 + 292);
            B0[0][1] = *(const fx4*)(bP0 + 292);
            B0[1][1] = *(const fx4*)(bP1 + 292);
            B0[2][1] = *(const fx4*)(bP2 + 292);
            B0[3][1] = *(const fx4*)(bP3 + 292);
        }
        compute(A0, B0);
    }

    // --- masked threshold count. C/D: col = ct*16 + (l&15), row = rt*16 + (l>>4)*4 + r ---
    const float thr = *thr_p;
    int am[2][4];
#pragma unroll
    for (int rt = 0; rt < 2; ++rt)
#pragma unroll
        for (int r = 0; r < 4; ++r)
            am[rt][r] = m1[slot * W1_ + rowHalf * 32 + rt * 16 + (l >> 4) * 4 + r];
    int bm[4];
#pragma unroll
    for (int ct = 0; ct < 4; ++ct)
        bm[ct] = m2[slot * W2_ + colHalf * 64 + ct * 16 + lr];

    int lc = 0;
#pragma unroll
    for (int rt = 0; rt < 2; ++rt)
#pragma unroll
        for (int ct = 0; ct < 4; ++ct)
#pragma unroll
            for (int r = 0; r < 4; ++r)
                lc += ((acc[rt][ct][r] >= thr) & (am[rt][r] != 0) & (bm[ct] != 0)) ? 1 : 0;
#pragma unroll
    for (int o = 32; o > 0; o >>= 1) lc += __shfl_down(lc, o);
    if (l == 0) atomicAdd(&cnt[slot], lc);   // device-scope, cross-XCD safe
}

// Finalize: norm = cnt / nA (nA recomputed from m1), then MLP head.
__global__ __launch_bounds__(256) void finalize_head(
    const int* __restrict__ cnt, const int* __restrict__ m1,
    const float* __restrict__ Wh,   // (S, HID) row-major
    const float* __restrict__ Ws,   // (HID, 1)
    float* __restrict__ out)
{
    int b = blockIdx.x * blockDim.x + threadIdx.x;
    if (b >= B_) return;
    float n[4];
#pragma unroll
    for (int s = 0; s < 4; ++s) {
        const int slot = b * 4 + s;
        int nA = 0;
        const int4* mp = (const int4*)(m1 + slot * W1_);
#pragma unroll
        for (int g = 0; g < 16; ++g) {
            int4 v = mp[g];
            nA += (v.x != 0) + (v.y != 0) + (v.z != 0) + (v.w != 0);
        }
        const float divisor = (nA == 0) ? 1e-7f : (float)nA;
        n[s] = (float)cnt[slot] / divisor;
    }
    float score = 0.f;
#pragma unroll
    for (int j = 0; j < HID_; ++j) {
        float h = n[0] * Wh[0 * HID_ + j] + n[1] * Wh[1 * HID_ + j]
                + n[2] * Wh[2 * HID_ + j] + n[3] * Wh[3 * HID_ + j];
        h = tanhf(h);
        score += h * Ws[j];
    }
    out[b] = 1.f / (1.f + expf(-score));
}

extern "C" void kernel_launch(void* const* d_in, const int* in_sizes, int n_in,
                              void* d_out, int out_size, void* d_ws, size_t ws_size,
                              hipStream_t stream)
{
    const float* t1  = (const float*)d_in[0];
    const float* t2  = (const float*)d_in[1];
    const int*   m1  = (const int*)d_in[2];
    const int*   m2  = (const int*)d_in[3];
    const float* thr = (const float*)d_in[4];
    const float* Wh  = (const float*)d_in[5];
    const float* Ws  = (const float*)d_in[6];
    float* out = (float*)d_out;
    int*   cnt = (int*)d_ws;   // 1024 ints

    hipMemsetAsync(cnt, 0, B_ * S_ * sizeof(int), stream);
    sim_count_mfma<<<B_ * S_, 256, 0, stream>>>(t1, t2, m1, m2, thr, cnt);
    finalize_head<<<1, 256, 0, stream>>>(cnt, m1, Wh, Ws, out);
}